// Round 10
// baseline (3609.488 us; speedup 1.0000x reference)
//
#include <hip/hip_runtime.h>
#include <math.h>

typedef unsigned long long ull;

// ---------------------------------------------------------------------------
// stem + P0 passthrough
// ---------------------------------------------------------------------------
__global__ __launch_bounds__(256) void stem_fused(const float* __restrict__ xyz,
    const float* __restrict__ w, const float* __restrict__ bias,
    float* __restrict__ F0, float* __restrict__ P0o, int N){
  int id = blockIdx.x*256 + threadIdx.x;
  int n = id % N; int b = id / N;
  float x = xyz[((size_t)b*3+0)*N+n];
  float y = xyz[((size_t)b*3+1)*N+n];
  float z = xyz[((size_t)b*3+2)*N+n];
  P0o[((size_t)b*3+0)*N+n] = x;
  P0o[((size_t)b*3+1)*N+n] = y;
  P0o[((size_t)b*3+2)*N+n] = z;
  #pragma unroll
  for (int o=0;o<8;o++){
    float v = fmaf(w[o*3+0],x, fmaf(w[o*3+1],y, fmaf(w[o*3+2],z, bias[o])));
    F0[((size_t)b*8+o)*N+n] = v;
  }
}

// ---------------------------------------------------------------------------
// KNN fused (scan + merge) — proven
// ---------------------------------------------------------------------------
__global__ __launch_bounds__(256) void knn_fused(
    const float* __restrict__ Pq, const float* __restrict__ Pp,
    int* __restrict__ idxk, int Nq, int Np){
  __shared__ float4 tile[4][256];
  __shared__ float  pd[16][4][64];
  __shared__ int    pi[16][4][64];
  int t = threadIdx.x, w = t>>6, l = t&63;
  int b = blockIdx.y;
  int qn = blockIdx.x*64 + l;
  const float* Pqb = Pq + (size_t)b*3*Nq;
  const float* Ppb = Pp + (size_t)b*3*Np;
  float qx = Pqb[qn], qy = Pqb[Nq+qn], qz = Pqb[2*Nq+qn];
  float qq = __fadd_rn(__fadd_rn(__fmul_rn(qx,qx),__fmul_rn(qy,qy)),__fmul_rn(qz,qz));

  float dl[16]; int il[16];
  #pragma unroll
  for (int u=0;u<16;u++){ dl[u]=INFINITY; il[u]=-1; }
  float maxd = INFINITY; int maxslot = 0;

  int CANDS = Np >> 2;
  int c0 = w*CANDS;
  for (int tb=0; tb<CANDS; tb+=256){
    __syncthreads();
    #pragma unroll
    for (int k=0;k<4;k++){
      int p = c0 + tb + k*64 + l;
      float px = Ppb[p], py = Ppb[Np+p], pz = Ppb[2*Np+p];
      float pp = __fadd_rn(__fadd_rn(__fmul_rn(px,px),__fmul_rn(py,py)),__fmul_rn(pz,pz));
      tile[w][k*64+l] = make_float4(px,py,pz,pp);
    }
    __syncthreads();
    for (int j=0;j<256;j++){
      float4 c = tile[w][j];
      float dot = __fadd_rn(__fadd_rn(__fmul_rn(qx,c.x),__fmul_rn(qy,c.y)),__fmul_rn(qz,c.z));
      float dc  = __fsub_rn(__fadd_rn(qq,c.w), __fmul_rn(2.0f,dot));
      if (dc < maxd){
        int pidx = c0 + tb + j;
        #pragma unroll
        for (int u=0;u<16;u++){ bool sel=(maxslot==u); dl[u]=sel?dc:dl[u]; il[u]=sel?pidx:il[u]; }
        maxd = dl[0]; maxslot = 0;
        #pragma unroll
        for (int u=1;u<16;u++){ bool g=(dl[u]>maxd); maxd=g?dl[u]:maxd; maxslot=g?u:maxslot; }
      }
    }
  }
  #pragma unroll
  for (int u=0;u<16;u++){ pd[u][w][l]=dl[u]; pi[u][w][l]=il[u]; }
  __syncthreads();
  if (t < 64){
    int q = t;
    float mdl[16]; int mil[16];
    #pragma unroll
    for (int u=0;u<16;u++){ mdl[u]=INFINITY; mil[u]=0x7fffffff; }
    float mmaxd = INFINITY; int mmaxi = 0x7fffffff; int mslot = 0;
    for (int s=0;s<4;s++){
      #pragma unroll
      for (int u=0;u<16;u++){
        float d = pd[u][s][q]; int ii = pi[u][s][q];
        bool better = (d < mmaxd) || (d == mmaxd && ii < mmaxi);
        if (better){
          #pragma unroll
          for (int v=0;v<16;v++){ bool sel=(mslot==v); mdl[v]=sel?d:mdl[v]; mil[v]=sel?ii:mil[v]; }
          mmaxd = mdl[0]; mmaxi = mil[0]; mslot = 0;
          #pragma unroll
          for (int v=1;v<16;v++){
            bool g = (mdl[v]>mmaxd) || (mdl[v]==mmaxd && mil[v]>mmaxi);
            mmaxd=g?mdl[v]:mmaxd; mmaxi=g?mil[v]:mmaxi; mslot=g?v:mslot;
          }
        }
      }
    }
    #pragma unroll
    for (int u=0;u<16;u++)
      idxk[((size_t)b*Nq + blockIdx.x*64 + q)*16 + u] = mil[u];
  }
}

// ---------------------------------------------------------------------------
// EdgeConv pre-activation + per-wave GN stats partials
// ---------------------------------------------------------------------------
template<int CIN, int COUT>
__global__ __launch_bounds__(1024) void edge_conv_pre(
    const float* __restrict__ Fk, const float* __restrict__ Fi,
    const int* __restrict__ idx, const float* __restrict__ W,
    float* __restrict__ pre, float* __restrict__ partS,
    float* __restrict__ partQ, int pstride, int Nq, int Np){
  constexpr int C2  = 2*CIN;
  constexpr int PAD = C2 + 4;
  constexpr int TO  = (COUT <= 64) ? COUT : 64;
  constexpr int OP  = COUT / TO;
  constexpr int CPG = COUT/8;
  constexpr int WPG = CPG/4;
  extern __shared__ float sm[];
  float* Wl = sm;
  float* Pl = sm + COUT*PAD;
  int t = threadIdx.x;
  int n = blockIdx.x, b = blockIdx.y;
  for (int e=t; e<COUT*C2; e += blockDim.x){
    int o=e/C2, c=e%C2; Wl[o*PAD+c] = W[e];
  }
  const int* idxn = idx + ((size_t)b*Nq + n)*16;
  for (int e=t; e<16*C2; e += blockDim.x){
    int k = e/C2, c = e%C2;
    int cc = (c < CIN) ? c : (c-CIN);
    float fi = Fi[((size_t)b*CIN + cc)*Nq + n];
    float v;
    if (c < CIN){ int nb = idxn[k]; v = Fk[((size_t)b*CIN + c)*Np + nb] - fi; }
    else v = fi;
    Pl[k*PAD+c] = v;
  }
  __syncthreads();
  int k = t & 15, o0 = t >> 4;
  float accv[OP];
  #pragma unroll
  for (int op=0; op<OP; op++){
    int o = o0 + op*TO;
    float acc = 0.f;
    #pragma unroll
    for (int c=0;c<C2;c+=4){
      float4 wv = *(const float4*)&Wl[o*PAD+c];
      float4 pv = *(const float4*)&Pl[k*PAD+c];
      acc = fmaf(wv.x,pv.x,acc); acc = fmaf(wv.y,pv.y,acc);
      acc = fmaf(wv.z,pv.z,acc); acc = fmaf(wv.w,pv.w,acc);
    }
    accv[op] = acc;
    pre[(((size_t)b*COUT + o)*Nq + n)*16 + k] = acc;
  }
  int w = t>>6;
  #pragma unroll
  for (int op=0; op<OP; op++){
    float s1 = accv[op], s2 = accv[op]*accv[op];
    #pragma unroll
    for (int off=32; off>=1; off>>=1){ s1 += __shfl_down(s1,off); s2 += __shfl_down(s2,off); }
    if ((t&63)==0){
      int o = o0 + op*TO;
      int g = o / CPG;
      int slot = n*WPG + (w % WPG);
      partS[((size_t)(b*8+g))*pstride + slot] = s1;
      partQ[((size_t)(b*8+g))*pstride + slot] = s2;
    }
  }
}

// combine partials -> per-(b,g) mu, rstd
__global__ __launch_bounds__(256) void gn_combine(const float* __restrict__ partS,
    const float* __restrict__ partQ, float2* __restrict__ stats,
    int nslot, int pstride, double cnt){
  int bg = blockIdx.x, t = threadIdx.x;
  const float* ps = partS + (size_t)bg*pstride;
  const float* pq = partQ + (size_t)bg*pstride;
  double s=0.0, q=0.0;
  for (int i=t; i<nslot; i+=256){ s += (double)ps[i]; q += (double)pq[i]; }
  #pragma unroll
  for (int off=32; off>=1; off>>=1){ s += __shfl_down(s,off); q += __shfl_down(q,off); }
  __shared__ double ls[4], lq[4];
  int wid = t>>6;
  if ((t&63)==0){ ls[wid]=s; lq[wid]=q; }
  __syncthreads();
  if (t==0){
    double S=ls[0]+ls[1]+ls[2]+ls[3], Q=lq[0]+lq[1]+lq[2]+lq[3];
    double mu = S/cnt;
    double var = Q/cnt - mu*mu;
    stats[bg] = make_float2((float)mu, (float)(1.0/sqrt(var+1e-5)));
  }
}

// normalize + affine + relu + max over K (single pre read, full grid)
template<int COUT>
__global__ __launch_bounds__(256) void gn_apply(const float* __restrict__ pre,
    const float2* __restrict__ stats, const float* __restrict__ gamma,
    const float* __restrict__ beta, float* __restrict__ outF, int Nq){
  int id = blockIdx.x*256 + threadIdx.x;
  int o = (id/Nq)%COUT; int b = id/(Nq*COUT);
  int g = o/(COUT/8);
  float2 st = stats[b*8+g];
  float muf = st.x, rstd = st.y;
  float ga=gamma[o], be=beta[o];
  const float4* p = (const float4*)(pre + (size_t)id*16);
  float m = 0.f;
  #pragma unroll
  for (int q=0;q<4;q++){
    float4 v = p[q];
    m = fmaxf(m, fmaf((v.x-muf)*rstd, ga, be));
    m = fmaxf(m, fmaf((v.y-muf)*rstd, ga, be));
    m = fmaxf(m, fmaf((v.z-muf)*rstd, ga, be));
    m = fmaxf(m, fmaf((v.w-muf)*rstd, ga, be));
  }
  outF[id] = m;
}

// single-kernel GN for small stages (pre is L2-resident): stats + apply
template<int COUT>
__global__ __launch_bounds__(1024) void gn_fused(const float* __restrict__ pre,
    const float* __restrict__ gamma, const float* __restrict__ beta,
    float* __restrict__ outF, int Nq){
  constexpr int CPG = COUT/8;
  int g = blockIdx.x, b = blockIdx.y, t = threadIdx.x;
  size_t base = (((size_t)b*COUT + g*CPG)*(size_t)Nq)*16;
  const float* p = pre + base;
  int len = CPG*Nq*16;
  double s=0.0, sq=0.0;
  for (int i = t*4; i < len; i += 4096){
    float4 v = *(const float4*)(p+i);
    s += (double)v.x; sq = fma((double)v.x,(double)v.x,sq);
    s += (double)v.y; sq = fma((double)v.y,(double)v.y,sq);
    s += (double)v.z; sq = fma((double)v.z,(double)v.z,sq);
    s += (double)v.w; sq = fma((double)v.w,(double)v.w,sq);
  }
  #pragma unroll
  for (int off=32; off>=1; off>>=1){ s += __shfl_down(s, off); sq += __shfl_down(sq, off); }
  __shared__ double ls[16], lq[16];
  __shared__ float stats[2];
  int wid = t>>6;
  if ((t&63)==0){ ls[wid]=s; lq[wid]=sq; }
  __syncthreads();
  if (t==0){
    double S=0.0, Q=0.0;
    #pragma unroll
    for (int w=0;w<16;w++){ S+=ls[w]; Q+=lq[w]; }
    double cnt = (double)CPG*(double)Nq*16.0;
    double mu  = S/cnt;
    double var = Q/cnt - mu*mu;
    stats[0] = (float)mu;
    stats[1] = (float)(1.0/sqrt(var+1e-5));
  }
  __syncthreads();
  float muf = stats[0], rstd = stats[1];
  int outs = CPG*Nq;
  for (int e=t; e<outs; e+=1024){
    int ol = e/Nq, n = e - ol*Nq;
    int o = g*CPG + ol;
    float ga = gamma[o], be = beta[o];
    const float4* pp = (const float4*)(p + (size_t)e*16);
    float m = 0.f;
    #pragma unroll
    for (int q=0;q<4;q++){
      float4 v = pp[q];
      m = fmaxf(m, fmaf((v.x-muf)*rstd, ga, be));
      m = fmaxf(m, fmaf((v.y-muf)*rstd, ga, be));
      m = fmaxf(m, fmaf((v.z-muf)*rstd, ga, be));
      m = fmaxf(m, fmaf((v.w-muf)*rstd, ga, be));
    }
    outF[((size_t)b*COUT + o)*Nq + n] = m;
  }
}

// ---------------------------------------------------------------------------
// FPS v8: BLK=512 / PPT=16, pinned register state, round-7 simple argmax
// chain (split-argmax reverted — issue-bound, split regressed). Halves the
// per-wave update issue time vs BLK=256/PPT=32; serial reduce grows only
// by 4 extra key reads. launch_bounds(512,2) caps VGPR at 256 (no spill,
// state needs ~95).
// ---------------------------------------------------------------------------
template<int CTRL>
__device__ __forceinline__ float dpp_maxf(float x){
  int y = __builtin_amdgcn_update_dpp(0, __float_as_int(x), CTRL, 0xf, 0xf, true);
  return fmaxf(x, __int_as_float(y));
}

template<int PPT, int BLK, int M>
__global__ __launch_bounds__(BLK, 2) void fps_kernel(const float* __restrict__ P,
    int* __restrict__ idx_out){
  constexpr int N  = PPT*BLK;
  constexpr int NW = BLK/64;
  extern __shared__ __align__(16) float sm[];
  float* lx = sm; float* ly = sm+N; float* lz = sm+2*N;
  ull* wk = (ull*)(sm + 3*N);
  int b = blockIdx.x, t = threadIdx.x;
  const float* Pb = P + (size_t)b*3*N;
  for (int i=t; i<N; i+=BLK){ lx[i]=Pb[i]; ly[i]=Pb[N+i]; lz[i]=Pb[2*N+i]; }
  __syncthreads();
  float px[PPT], py[PPT], pz[PPT], dist[PPT];
  #pragma unroll
  for (int j=0;j<PPT;j++){ int p=t*PPT+j; px[j]=lx[p]; py[j]=ly[p]; pz[j]=lz[p]; }
  #pragma unroll
  for (int j=0;j<PPT;j++){
    asm volatile("" : "+v"(px[j]), "+v"(py[j]), "+v"(pz[j]));
  }
  float sx = lx[0], sy = ly[0], sz = lz[0];
  float bd = -1.f; int bj = 0;
  #pragma unroll
  for (int j=0;j<PPT;j++){
    float dx=__fsub_rn(px[j],sx), dy=__fsub_rn(py[j],sy), dz=__fsub_rn(pz[j],sz);
    float dd=__fadd_rn(__fadd_rn(__fmul_rn(dx,dx),__fmul_rn(dy,dy)),__fmul_rn(dz,dz));
    dist[j]=dd;
    bool c = dd > bd; bd = c?dd:bd; bj = c?j:bj;
  }
  int pbest = t*PPT + bj;
  if (t==0) idx_out[(size_t)b*M] = 0;
  int wid = t>>6, lane = t&63, par = 0;
  for (int i=1;i<M;i++){
    float r = bd;
    r = dpp_maxf<0x111>(r); r = dpp_maxf<0x112>(r);
    r = dpp_maxf<0x114>(r); r = dpp_maxf<0x118>(r);
    r = dpp_maxf<0x142>(r); r = dpp_maxf<0x143>(r);
    float wmax = __int_as_float(__builtin_amdgcn_readlane(__float_as_int(r), 63));
    ull msk = __ballot(bd == wmax);
    int srcl = __ffsll(msk) - 1;
    int wp = __builtin_amdgcn_readlane(pbest, srcl);
    if (lane==0)
      wk[par*NW + wid] = ((ull)__float_as_uint(wmax)<<32)
                       | (unsigned)(~(unsigned)wp);
    __syncthreads();
    ull best = wk[par*NW];
    #pragma unroll
    for (int w=1;w<NW;w++){ ull o = wk[par*NW+w]; best = (o>best)?o:best; }
    unsigned widx = ~(unsigned)best;
    if (t==0) idx_out[(size_t)b*M + i] = (int)widx;
    float nsx = lx[widx], nsy = ly[widx], nsz = lz[widx];
    par ^= 1;
    float nbd = -1.f; int nbj = 0;
    #pragma unroll
    for (int j=0;j<PPT;j++){
      float dx=__fsub_rn(px[j],nsx), dy=__fsub_rn(py[j],nsy), dz=__fsub_rn(pz[j],nsz);
      float dd=__fadd_rn(__fadd_rn(__fmul_rn(dx,dx),__fmul_rn(dy,dy)),__fmul_rn(dz,dz));
      float nd = fminf(dist[j], dd);
      dist[j] = nd;
      bool c = nd > nbd; nbd = c?nd:nbd; nbj = c?j:nbj;
    }
    bd = nbd; pbest = t*PPT + nbj;
  }
}

// ---------------------------------------------------------------------------
// fused gather
// ---------------------------------------------------------------------------
__global__ __launch_bounds__(256) void gather_fused(float* __restrict__ Pdst,
    const float* __restrict__ Psrc, float* __restrict__ Fdst,
    const float* __restrict__ Fsrc, const int* __restrict__ idxv,
    int CF, int Nsrc, int M){
  int per = (3+CF)*M;
  int total = 2*per;
  for (int id = blockIdx.x*256 + threadIdx.x; id < total; id += gridDim.x*256){
    int b = id/per, r = id%per, c = r/M, m = r%M;
    int sn = idxv[(size_t)b*M + m];
    if (c < 3)
      Pdst[((size_t)b*3+c)*M+m] = Psrc[((size_t)b*3+c)*Nsrc+sn];
    else {
      int cf = c-3;
      Fdst[((size_t)b*CF+cf)*M+m] = Fsrc[((size_t)b*CF+cf)*Nsrc+sn];
    }
  }
}

// ---------------------------------------------------------------------------
extern "C" void kernel_launch(void* const* d_in, const int* in_sizes, int n_in,
                              void* d_out, int out_size, void* d_ws, size_t ws_size,
                              hipStream_t stream) {
  const float* xyz    = (const float*)d_in[0];
  const float* stem_w = (const float*)d_in[1];
  const float* stem_b = (const float*)d_in[2];
  const float* w1 = (const float*)d_in[3];
  const float* g1 = (const float*)d_in[4];
  const float* b1 = (const float*)d_in[5];
  const float* w2 = (const float*)d_in[6];
  const float* g2 = (const float*)d_in[7];
  const float* b2 = (const float*)d_in[8];
  const float* w3 = (const float*)d_in[9];
  const float* g3 = (const float*)d_in[10];
  const float* b3 = (const float*)d_in[11];
  const float* w4 = (const float*)d_in[12];
  const float* g4 = (const float*)d_in[13];
  const float* b4 = (const float*)d_in[14];

  float* out = (float*)d_out;
  float* P0o  = out + 0;
  float* F0a  = out + 49152;
  float* P1o  = out + 573440;
  float* F1a  = out + 585728;
  float* P2o  = out + 847872;
  float* F2a  = out + 850944;

  char* ws = (char*)d_ws;
  float* F0     = (float*)(ws + 0);            // 512 KB
  float* pre    = (float*)(ws + 524288);       // up to 33.5 MB
  int*   idxk   = (int*)  (ws + 34078720);     // 1 MB
  float2* stats = (float2*)(ws + 35127296);    // 128 B
  int*   idx1   = (int*)  (ws + 35127424);     // 16 KB
  int*   idx2   = (int*)  (ws + 35143808);     // 4 KB
  float* F1sk   = (float*)(ws + 35147904);     // 512 KB
  float* F2sk   = (float*)(ws + 35672192);     // 256 KB
  float* F2mid  = (float*)(ws + 35934336);     // 256 KB
  float* pS1 = (float*)(ws + 35147904);        // stage-1 partials (overlap F1sk/F2sk — dead then)
  float* pQ1 = (float*)(ws + 35672192);
  float* pS2 = (float*)(ws + 17825792);        // stage-2..4 partials (pre tail)
  float* pQ2 = (float*)(ws + 18087936);

  size_t smem_c1 = (size_t)(32*20  + 16*20 )*4;
  size_t smem_c2 = (size_t)(64*68  + 16*68 )*4;
  size_t smem_c3 = (size_t)(64*132 + 16*132)*4;
  size_t smem_c4 = (size_t)(128*132+ 16*132)*4;
  size_t smem_f1 = (size_t)3*8192*4 + 256;
  size_t smem_f2 = (size_t)3*2048*4 + 256;

  // ---- stage 1
  stem_fused<<<64, 256, 0, stream>>>(xyz, stem_w, stem_b, F0, P0o, 8192);
  knn_fused<<<dim3(128,2), 256, 0, stream>>>(xyz, xyz, idxk, 8192, 8192);
  edge_conv_pre<8,32><<<dim3(8192,2), 512, smem_c1, stream>>>(F0, F0, idxk, w1, pre, pS1, pQ1, 8192, 8192, 8192);
  gn_combine<<<16, 256, 0, stream>>>(pS1, pQ1, stats, 8192, 8192, 524288.0);
  gn_apply<32><<<2048, 256, 0, stream>>>(pre, stats, g1, b1, F0a, 8192);

  // ---- FPS 8192 -> 2048 + gathers
  fps_kernel<16,512,2048><<<2, 512, smem_f1, stream>>>(xyz, idx1);
  gather_fused<<<560, 256, 0, stream>>>(P1o, xyz, F1sk, F0a, idx1, 32, 8192, 2048);

  // ---- stage 2
  knn_fused<<<dim3(32,2), 256, 0, stream>>>(P1o, xyz, idxk, 2048, 8192);
  edge_conv_pre<32,64><<<dim3(2048,2), 1024, smem_c2, stream>>>(F0a, F1sk, idxk, w2, pre, pS2, pQ2, 4096, 2048, 8192);
  gn_combine<<<16, 256, 0, stream>>>(pS2, pQ2, stats, 4096, 4096, 262144.0);
  gn_apply<64><<<1024, 256, 0, stream>>>(pre, stats, g2, b2, F1a, 2048);

  // ---- FPS 2048 -> 512 + gathers
  fps_kernel<4,512,512><<<2, 512, smem_f2, stream>>>(P1o, idx2);
  gather_fused<<<268, 256, 0, stream>>>(P2o, P1o, F2sk, F1a, idx2, 64, 2048, 512);

  // ---- stage 3 (small: single-kernel GN, pre is L2-resident)
  knn_fused<<<dim3(8,2), 256, 0, stream>>>(P2o, P1o, idxk, 512, 2048);
  edge_conv_pre<64,64><<<dim3(512,2), 1024, smem_c3, stream>>>(F1a, F2sk, idxk, w3, pre, pS2, pQ2, 4096, 512, 2048);
  gn_fused<64><<<dim3(8,2), 1024, 0, stream>>>(pre, g3, b3, F2mid, 512);

  // ---- stage 4 (same knn idx)
  edge_conv_pre<64,128><<<dim3(512,2), 1024, smem_c4, stream>>>(F1a, F2mid, idxk, w4, pre, pS2, pQ2, 4096, 512, 2048);
  gn_fused<128><<<dim3(8,2), 1024, 0, stream>>>(pre, g4, b4, F2a, 512);

  (void)in_sizes; (void)n_in; (void)out_size; (void)ws_size;
}

// Round 11
// 3548.605 us; speedup vs baseline: 1.0172x; 1.0172x over previous
//
#include <hip/hip_runtime.h>
#include <math.h>

typedef unsigned long long ull;

// ---------------------------------------------------------------------------
// stem + P0 passthrough
// ---------------------------------------------------------------------------
__global__ __launch_bounds__(256) void stem_fused(const float* __restrict__ xyz,
    const float* __restrict__ w, const float* __restrict__ bias,
    float* __restrict__ F0, float* __restrict__ P0o, int N){
  int id = blockIdx.x*256 + threadIdx.x;
  int n = id % N; int b = id / N;
  float x = xyz[((size_t)b*3+0)*N+n];
  float y = xyz[((size_t)b*3+1)*N+n];
  float z = xyz[((size_t)b*3+2)*N+n];
  P0o[((size_t)b*3+0)*N+n] = x;
  P0o[((size_t)b*3+1)*N+n] = y;
  P0o[((size_t)b*3+2)*N+n] = z;
  #pragma unroll
  for (int o=0;o<8;o++){
    float v = fmaf(w[o*3+0],x, fmaf(w[o*3+1],y, fmaf(w[o*3+2],z, bias[o])));
    F0[((size_t)b*8+o)*N+n] = v;
  }
}

// ---------------------------------------------------------------------------
// KNN fused (scan + merge) — proven
// ---------------------------------------------------------------------------
__global__ __launch_bounds__(256) void knn_fused(
    const float* __restrict__ Pq, const float* __restrict__ Pp,
    int* __restrict__ idxk, int Nq, int Np){
  __shared__ float4 tile[4][256];
  __shared__ float  pd[16][4][64];
  __shared__ int    pi[16][4][64];
  int t = threadIdx.x, w = t>>6, l = t&63;
  int b = blockIdx.y;
  int qn = blockIdx.x*64 + l;
  const float* Pqb = Pq + (size_t)b*3*Nq;
  const float* Ppb = Pp + (size_t)b*3*Np;
  float qx = Pqb[qn], qy = Pqb[Nq+qn], qz = Pqb[2*Nq+qn];
  float qq = __fadd_rn(__fadd_rn(__fmul_rn(qx,qx),__fmul_rn(qy,qy)),__fmul_rn(qz,qz));

  float dl[16]; int il[16];
  #pragma unroll
  for (int u=0;u<16;u++){ dl[u]=INFINITY; il[u]=-1; }
  float maxd = INFINITY; int maxslot = 0;

  int CANDS = Np >> 2;
  int c0 = w*CANDS;
  for (int tb=0; tb<CANDS; tb+=256){
    __syncthreads();
    #pragma unroll
    for (int k=0;k<4;k++){
      int p = c0 + tb + k*64 + l;
      float px = Ppb[p], py = Ppb[Np+p], pz = Ppb[2*Np+p];
      float pp = __fadd_rn(__fadd_rn(__fmul_rn(px,px),__fmul_rn(py,py)),__fmul_rn(pz,pz));
      tile[w][k*64+l] = make_float4(px,py,pz,pp);
    }
    __syncthreads();
    for (int j=0;j<256;j++){
      float4 c = tile[w][j];
      float dot = __fadd_rn(__fadd_rn(__fmul_rn(qx,c.x),__fmul_rn(qy,c.y)),__fmul_rn(qz,c.z));
      float dc  = __fsub_rn(__fadd_rn(qq,c.w), __fmul_rn(2.0f,dot));
      if (dc < maxd){
        int pidx = c0 + tb + j;
        #pragma unroll
        for (int u=0;u<16;u++){ bool sel=(maxslot==u); dl[u]=sel?dc:dl[u]; il[u]=sel?pidx:il[u]; }
        maxd = dl[0]; maxslot = 0;
        #pragma unroll
        for (int u=1;u<16;u++){ bool g=(dl[u]>maxd); maxd=g?dl[u]:maxd; maxslot=g?u:maxslot; }
      }
    }
  }
  #pragma unroll
  for (int u=0;u<16;u++){ pd[u][w][l]=dl[u]; pi[u][w][l]=il[u]; }
  __syncthreads();
  if (t < 64){
    int q = t;
    float mdl[16]; int mil[16];
    #pragma unroll
    for (int u=0;u<16;u++){ mdl[u]=INFINITY; mil[u]=0x7fffffff; }
    float mmaxd = INFINITY; int mmaxi = 0x7fffffff; int mslot = 0;
    for (int s=0;s<4;s++){
      #pragma unroll
      for (int u=0;u<16;u++){
        float d = pd[u][s][q]; int ii = pi[u][s][q];
        bool better = (d < mmaxd) || (d == mmaxd && ii < mmaxi);
        if (better){
          #pragma unroll
          for (int v=0;v<16;v++){ bool sel=(mslot==v); mdl[v]=sel?d:mdl[v]; mil[v]=sel?ii:mil[v]; }
          mmaxd = mdl[0]; mmaxi = mil[0]; mslot = 0;
          #pragma unroll
          for (int v=1;v<16;v++){
            bool g = (mdl[v]>mmaxd) || (mdl[v]==mmaxd && mil[v]>mmaxi);
            mmaxd=g?mdl[v]:mmaxd; mmaxi=g?mil[v]:mmaxi; mslot=g?v:mslot;
          }
        }
      }
    }
    #pragma unroll
    for (int u=0;u<16;u++)
      idxk[((size_t)b*Nq + blockIdx.x*64 + q)*16 + u] = mil[u];
  }
}

// ---------------------------------------------------------------------------
// EdgeConv pre-activation + per-wave GN stats partials
// ---------------------------------------------------------------------------
template<int CIN, int COUT>
__global__ __launch_bounds__(1024) void edge_conv_pre(
    const float* __restrict__ Fk, const float* __restrict__ Fi,
    const int* __restrict__ idx, const float* __restrict__ W,
    float* __restrict__ pre, float* __restrict__ partS,
    float* __restrict__ partQ, int pstride, int Nq, int Np){
  constexpr int C2  = 2*CIN;
  constexpr int PAD = C2 + 4;
  constexpr int TO  = (COUT <= 64) ? COUT : 64;
  constexpr int OP  = COUT / TO;
  constexpr int CPG = COUT/8;
  constexpr int WPG = CPG/4;
  extern __shared__ float sm[];
  float* Wl = sm;
  float* Pl = sm + COUT*PAD;
  int t = threadIdx.x;
  int n = blockIdx.x, b = blockIdx.y;
  for (int e=t; e<COUT*C2; e += blockDim.x){
    int o=e/C2, c=e%C2; Wl[o*PAD+c] = W[e];
  }
  const int* idxn = idx + ((size_t)b*Nq + n)*16;
  for (int e=t; e<16*C2; e += blockDim.x){
    int k = e/C2, c = e%C2;
    int cc = (c < CIN) ? c : (c-CIN);
    float fi = Fi[((size_t)b*CIN + cc)*Nq + n];
    float v;
    if (c < CIN){ int nb = idxn[k]; v = Fk[((size_t)b*CIN + c)*Np + nb] - fi; }
    else v = fi;
    Pl[k*PAD+c] = v;
  }
  __syncthreads();
  int k = t & 15, o0 = t >> 4;
  float accv[OP];
  #pragma unroll
  for (int op=0; op<OP; op++){
    int o = o0 + op*TO;
    float acc = 0.f;
    #pragma unroll
    for (int c=0;c<C2;c+=4){
      float4 wv = *(const float4*)&Wl[o*PAD+c];
      float4 pv = *(const float4*)&Pl[k*PAD+c];
      acc = fmaf(wv.x,pv.x,acc); acc = fmaf(wv.y,pv.y,acc);
      acc = fmaf(wv.z,pv.z,acc); acc = fmaf(wv.w,pv.w,acc);
    }
    accv[op] = acc;
    pre[(((size_t)b*COUT + o)*Nq + n)*16 + k] = acc;
  }
  int w = t>>6;
  #pragma unroll
  for (int op=0; op<OP; op++){
    float s1 = accv[op], s2 = accv[op]*accv[op];
    #pragma unroll
    for (int off=32; off>=1; off>>=1){ s1 += __shfl_down(s1,off); s2 += __shfl_down(s2,off); }
    if ((t&63)==0){
      int o = o0 + op*TO;
      int g = o / CPG;
      int slot = n*WPG + (w % WPG);
      partS[((size_t)(b*8+g))*pstride + slot] = s1;
      partQ[((size_t)(b*8+g))*pstride + slot] = s2;
    }
  }
}

// combine partials -> per-(b,g) mu, rstd
__global__ __launch_bounds__(256) void gn_combine(const float* __restrict__ partS,
    const float* __restrict__ partQ, float2* __restrict__ stats,
    int nslot, int pstride, double cnt){
  int bg = blockIdx.x, t = threadIdx.x;
  const float* ps = partS + (size_t)bg*pstride;
  const float* pq = partQ + (size_t)bg*pstride;
  double s=0.0, q=0.0;
  for (int i=t; i<nslot; i+=256){ s += (double)ps[i]; q += (double)pq[i]; }
  #pragma unroll
  for (int off=32; off>=1; off>>=1){ s += __shfl_down(s,off); q += __shfl_down(q,off); }
  __shared__ double ls[4], lq[4];
  int wid = t>>6;
  if ((t&63)==0){ ls[wid]=s; lq[wid]=q; }
  __syncthreads();
  if (t==0){
    double S=ls[0]+ls[1]+ls[2]+ls[3], Q=lq[0]+lq[1]+lq[2]+lq[3];
    double mu = S/cnt;
    double var = Q/cnt - mu*mu;
    stats[bg] = make_float2((float)mu, (float)(1.0/sqrt(var+1e-5)));
  }
}

// normalize + affine + relu + max over K (single pre read, full grid)
template<int COUT>
__global__ __launch_bounds__(256) void gn_apply(const float* __restrict__ pre,
    const float2* __restrict__ stats, const float* __restrict__ gamma,
    const float* __restrict__ beta, float* __restrict__ outF, int Nq){
  int id = blockIdx.x*256 + threadIdx.x;
  int o = (id/Nq)%COUT; int b = id/(Nq*COUT);
  int g = o/(COUT/8);
  float2 st = stats[b*8+g];
  float muf = st.x, rstd = st.y;
  float ga=gamma[o], be=beta[o];
  const float4* p = (const float4*)(pre + (size_t)id*16);
  float m = 0.f;
  #pragma unroll
  for (int q=0;q<4;q++){
    float4 v = p[q];
    m = fmaxf(m, fmaf((v.x-muf)*rstd, ga, be));
    m = fmaxf(m, fmaf((v.y-muf)*rstd, ga, be));
    m = fmaxf(m, fmaf((v.z-muf)*rstd, ga, be));
    m = fmaxf(m, fmaf((v.w-muf)*rstd, ga, be));
  }
  outF[id] = m;
}

// single-kernel GN for small stages (pre is L2-resident): stats + apply
template<int COUT>
__global__ __launch_bounds__(1024) void gn_fused(const float* __restrict__ pre,
    const float* __restrict__ gamma, const float* __restrict__ beta,
    float* __restrict__ outF, int Nq){
  constexpr int CPG = COUT/8;
  int g = blockIdx.x, b = blockIdx.y, t = threadIdx.x;
  size_t base = (((size_t)b*COUT + g*CPG)*(size_t)Nq)*16;
  const float* p = pre + base;
  int len = CPG*Nq*16;
  double s=0.0, sq=0.0;
  for (int i = t*4; i < len; i += 4096){
    float4 v = *(const float4*)(p+i);
    s += (double)v.x; sq = fma((double)v.x,(double)v.x,sq);
    s += (double)v.y; sq = fma((double)v.y,(double)v.y,sq);
    s += (double)v.z; sq = fma((double)v.z,(double)v.z,sq);
    s += (double)v.w; sq = fma((double)v.w,(double)v.w,sq);
  }
  #pragma unroll
  for (int off=32; off>=1; off>>=1){ s += __shfl_down(s, off); sq += __shfl_down(sq, off); }
  __shared__ double ls[16], lq[16];
  __shared__ float stats[2];
  int wid = t>>6;
  if ((t&63)==0){ ls[wid]=s; lq[wid]=sq; }
  __syncthreads();
  if (t==0){
    double S=0.0, Q=0.0;
    #pragma unroll
    for (int w=0;w<16;w++){ S+=ls[w]; Q+=lq[w]; }
    double cnt = (double)CPG*(double)Nq*16.0;
    double mu  = S/cnt;
    double var = Q/cnt - mu*mu;
    stats[0] = (float)mu;
    stats[1] = (float)(1.0/sqrt(var+1e-5));
  }
  __syncthreads();
  float muf = stats[0], rstd = stats[1];
  int outs = CPG*Nq;
  for (int e=t; e<outs; e+=1024){
    int ol = e/Nq, n = e - ol*Nq;
    int o = g*CPG + ol;
    float ga = gamma[o], be = beta[o];
    const float4* pp = (const float4*)(p + (size_t)e*16);
    float m = 0.f;
    #pragma unroll
    for (int q=0;q<4;q++){
      float4 v = pp[q];
      m = fmaxf(m, fmaf((v.x-muf)*rstd, ga, be));
      m = fmaxf(m, fmaf((v.y-muf)*rstd, ga, be));
      m = fmaxf(m, fmaf((v.z-muf)*rstd, ga, be));
      m = fmaxf(m, fmaf((v.w-muf)*rstd, ga, be));
    }
    outF[((size_t)b*COUT + o)*Nq + n] = m;
  }
}

// ---------------------------------------------------------------------------
// FPS v9: BLK=256 proven config + packed-FP32 distance math.
// v_pk_add_f32 / v_pk_mul_f32 process 2 points per instruction; each half is
// IEEE f32 round-to-nearest, no contraction -> bit-exact vs scalar chain.
// x - s computed as x + (-s) (IEEE-identical). min/argmax tail stays scalar,
// .x before .y with strict > -> reference first-occurrence tie semantics.
// ---------------------------------------------------------------------------
__device__ __forceinline__ float2 pk_add2(float2 a, float2 b){
  float2 d;
  asm("v_pk_add_f32 %0, %1, %2" : "=v"(d) : "v"(a), "v"(b));
  return d;
}
__device__ __forceinline__ float2 pk_mul2(float2 a, float2 b){
  float2 d;
  asm("v_pk_mul_f32 %0, %1, %2" : "=v"(d) : "v"(a), "v"(b));
  return d;
}
template<int CTRL>
__device__ __forceinline__ float dpp_maxf(float x){
  int y = __builtin_amdgcn_update_dpp(0, __float_as_int(x), CTRL, 0xf, 0xf, true);
  return fmaxf(x, __int_as_float(y));
}

template<int PPT, int BLK, int M>
__global__ __launch_bounds__(BLK, 1) void fps_kernel(const float* __restrict__ P,
    int* __restrict__ idx_out){
  constexpr int N  = PPT*BLK;
  constexpr int NW = BLK/64;
  constexpr int NP = PPT/2;
  extern __shared__ __align__(16) float sm[];
  float* lx = sm; float* ly = sm+N; float* lz = sm+2*N;
  ull* wk = (ull*)(sm + 3*N);
  int b = blockIdx.x, t = threadIdx.x;
  const float* Pb = P + (size_t)b*3*N;
  for (int i=t; i<N; i+=BLK){ lx[i]=Pb[i]; ly[i]=Pb[N+i]; lz[i]=Pb[2*N+i]; }
  __syncthreads();
  // register-resident owned points as float2 pairs (even LDS offsets)
  float2 px2[NP], py2[NP], pz2[NP];
  float dist[PPT];
  #pragma unroll
  for (int p=0;p<NP;p++){
    int e = t*PPT + 2*p;
    px2[p] = *(const float2*)&lx[e];
    py2[p] = *(const float2*)&ly[e];
    pz2[p] = *(const float2*)&lz[e];
  }
  #pragma unroll
  for (int p=0;p<NP;p++){
    asm volatile("" : "+v"(px2[p]), "+v"(py2[p]), "+v"(pz2[p]));
  }
  // initial distances to original index 0
  {
    float sx = lx[0], sy = ly[0], sz = lz[0];
    float2 nsx2 = make_float2(-sx,-sx);
    float2 nsy2 = make_float2(-sy,-sy);
    float2 nsz2 = make_float2(-sz,-sz);
    float bd0 = -1.f; int bj0 = 0;
    #pragma unroll
    for (int p=0;p<NP;p++){
      float2 dx2 = pk_add2(px2[p], nsx2);
      float2 dy2 = pk_add2(py2[p], nsy2);
      float2 dz2 = pk_add2(pz2[p], nsz2);
      float2 ss = pk_add2(pk_add2(pk_mul2(dx2,dx2), pk_mul2(dy2,dy2)), pk_mul2(dz2,dz2));
      dist[2*p] = ss.x;
      bool c0 = ss.x > bd0; bd0 = c0?ss.x:bd0; bj0 = c0?(2*p):bj0;
      dist[2*p+1] = ss.y;
      bool c1 = ss.y > bd0; bd0 = c1?ss.y:bd0; bj0 = c1?(2*p+1):bj0;
    }
    // enter loop state
    float bd = bd0; int pbest = t*PPT + bj0;
    if (t==0) idx_out[(size_t)b*M] = 0;
    int wid = t>>6, lane = t&63, par = 0;
    for (int i=1;i<M;i++){
      float r = bd;
      r = dpp_maxf<0x111>(r); r = dpp_maxf<0x112>(r);
      r = dpp_maxf<0x114>(r); r = dpp_maxf<0x118>(r);
      r = dpp_maxf<0x142>(r); r = dpp_maxf<0x143>(r);
      float wmax = __int_as_float(__builtin_amdgcn_readlane(__float_as_int(r), 63));
      ull msk = __ballot(bd == wmax);
      int srcl = __ffsll(msk) - 1;            // lowest lane == lowest owned index
      int wp = __builtin_amdgcn_readlane(pbest, srcl);
      if (lane==0)
        wk[par*NW + wid] = ((ull)__float_as_uint(wmax)<<32)
                         | (unsigned)(~(unsigned)wp);
      __syncthreads();
      ull best = wk[par*NW];
      #pragma unroll
      for (int w=1;w<NW;w++){ ull o = wk[par*NW+w]; best = (o>best)?o:best; }
      unsigned widx = ~(unsigned)best;
      if (t==0) idx_out[(size_t)b*M + i] = (int)widx;
      float nsx = lx[widx], nsy = ly[widx], nsz = lz[widx];
      par ^= 1;
      float2 sx2 = make_float2(-nsx,-nsx);
      float2 sy2 = make_float2(-nsy,-nsy);
      float2 sz2 = make_float2(-nsz,-nsz);
      float nbd = -1.f; int nbj = 0;
      #pragma unroll
      for (int p=0;p<NP;p++){
        float2 dx2 = pk_add2(px2[p], sx2);
        float2 dy2 = pk_add2(py2[p], sy2);
        float2 dz2 = pk_add2(pz2[p], sz2);
        float2 ss = pk_add2(pk_add2(pk_mul2(dx2,dx2), pk_mul2(dy2,dy2)), pk_mul2(dz2,dz2));
        float nd0 = fminf(dist[2*p], ss.x); dist[2*p] = nd0;
        bool c0 = nd0 > nbd; nbd = c0?nd0:nbd; nbj = c0?(2*p):nbj;
        float nd1 = fminf(dist[2*p+1], ss.y); dist[2*p+1] = nd1;
        bool c1 = nd1 > nbd; nbd = c1?nd1:nbd; nbj = c1?(2*p+1):nbj;
      }
      bd = nbd; pbest = t*PPT + nbj;
    }
  }
}

// ---------------------------------------------------------------------------
// fused gather
// ---------------------------------------------------------------------------
__global__ __launch_bounds__(256) void gather_fused(float* __restrict__ Pdst,
    const float* __restrict__ Psrc, float* __restrict__ Fdst,
    const float* __restrict__ Fsrc, const int* __restrict__ idxv,
    int CF, int Nsrc, int M){
  int per = (3+CF)*M;
  int total = 2*per;
  for (int id = blockIdx.x*256 + threadIdx.x; id < total; id += gridDim.x*256){
    int b = id/per, r = id%per, c = r/M, m = r%M;
    int sn = idxv[(size_t)b*M + m];
    if (c < 3)
      Pdst[((size_t)b*3+c)*M+m] = Psrc[((size_t)b*3+c)*Nsrc+sn];
    else {
      int cf = c-3;
      Fdst[((size_t)b*CF+cf)*M+m] = Fsrc[((size_t)b*CF+cf)*Nsrc+sn];
    }
  }
}

// ---------------------------------------------------------------------------
extern "C" void kernel_launch(void* const* d_in, const int* in_sizes, int n_in,
                              void* d_out, int out_size, void* d_ws, size_t ws_size,
                              hipStream_t stream) {
  const float* xyz    = (const float*)d_in[0];
  const float* stem_w = (const float*)d_in[1];
  const float* stem_b = (const float*)d_in[2];
  const float* w1 = (const float*)d_in[3];
  const float* g1 = (const float*)d_in[4];
  const float* b1 = (const float*)d_in[5];
  const float* w2 = (const float*)d_in[6];
  const float* g2 = (const float*)d_in[7];
  const float* b2 = (const float*)d_in[8];
  const float* w3 = (const float*)d_in[9];
  const float* g3 = (const float*)d_in[10];
  const float* b3 = (const float*)d_in[11];
  const float* w4 = (const float*)d_in[12];
  const float* g4 = (const float*)d_in[13];
  const float* b4 = (const float*)d_in[14];

  float* out = (float*)d_out;
  float* P0o  = out + 0;
  float* F0a  = out + 49152;
  float* P1o  = out + 573440;
  float* F1a  = out + 585728;
  float* P2o  = out + 847872;
  float* F2a  = out + 850944;

  char* ws = (char*)d_ws;
  float* F0     = (float*)(ws + 0);            // 512 KB
  float* pre    = (float*)(ws + 524288);       // up to 33.5 MB
  int*   idxk   = (int*)  (ws + 34078720);     // 1 MB
  float2* stats = (float2*)(ws + 35127296);    // 128 B
  int*   idx1   = (int*)  (ws + 35127424);     // 16 KB
  int*   idx2   = (int*)  (ws + 35143808);     // 4 KB
  float* F1sk   = (float*)(ws + 35147904);     // 512 KB
  float* F2sk   = (float*)(ws + 35672192);     // 256 KB
  float* F2mid  = (float*)(ws + 35934336);     // 256 KB
  float* pS1 = (float*)(ws + 35147904);        // stage-1 partials (overlap F1sk/F2sk — dead then)
  float* pQ1 = (float*)(ws + 35672192);
  float* pS2 = (float*)(ws + 17825792);        // stage-2..4 partials (pre tail)
  float* pQ2 = (float*)(ws + 18087936);

  size_t smem_c1 = (size_t)(32*20  + 16*20 )*4;
  size_t smem_c2 = (size_t)(64*68  + 16*68 )*4;
  size_t smem_c3 = (size_t)(64*132 + 16*132)*4;
  size_t smem_c4 = (size_t)(128*132+ 16*132)*4;
  size_t smem_f1 = (size_t)3*8192*4 + 256;
  size_t smem_f2 = (size_t)3*2048*4 + 256;

  // ---- stage 1
  stem_fused<<<64, 256, 0, stream>>>(xyz, stem_w, stem_b, F0, P0o, 8192);
  knn_fused<<<dim3(128,2), 256, 0, stream>>>(xyz, xyz, idxk, 8192, 8192);
  edge_conv_pre<8,32><<<dim3(8192,2), 512, smem_c1, stream>>>(F0, F0, idxk, w1, pre, pS1, pQ1, 8192, 8192, 8192);
  gn_combine<<<16, 256, 0, stream>>>(pS1, pQ1, stats, 8192, 8192, 524288.0);
  gn_apply<32><<<2048, 256, 0, stream>>>(pre, stats, g1, b1, F0a, 8192);

  // ---- FPS 8192 -> 2048 + gathers
  fps_kernel<32,256,2048><<<2, 256, smem_f1, stream>>>(xyz, idx1);
  gather_fused<<<560, 256, 0, stream>>>(P1o, xyz, F1sk, F0a, idx1, 32, 8192, 2048);

  // ---- stage 2
  knn_fused<<<dim3(32,2), 256, 0, stream>>>(P1o, xyz, idxk, 2048, 8192);
  edge_conv_pre<32,64><<<dim3(2048,2), 1024, smem_c2, stream>>>(F0a, F1sk, idxk, w2, pre, pS2, pQ2, 4096, 2048, 8192);
  gn_combine<<<16, 256, 0, stream>>>(pS2, pQ2, stats, 4096, 4096, 262144.0);
  gn_apply<64><<<1024, 256, 0, stream>>>(pre, stats, g2, b2, F1a, 2048);

  // ---- FPS 2048 -> 512 + gathers
  fps_kernel<8,256,512><<<2, 256, smem_f2, stream>>>(P1o, idx2);
  gather_fused<<<268, 256, 0, stream>>>(P2o, P1o, F2sk, F1a, idx2, 64, 2048, 512);

  // ---- stage 3 (small: single-kernel GN, pre is L2-resident)
  knn_fused<<<dim3(8,2), 256, 0, stream>>>(P2o, P1o, idxk, 512, 2048);
  edge_conv_pre<64,64><<<dim3(512,2), 1024, smem_c3, stream>>>(F1a, F2sk, idxk, w3, pre, pS2, pQ2, 4096, 512, 2048);
  gn_fused<64><<<dim3(8,2), 1024, 0, stream>>>(pre, g3, b3, F2mid, 512);

  // ---- stage 4 (same knn idx)
  edge_conv_pre<64,128><<<dim3(512,2), 1024, smem_c4, stream>>>(F1a, F2mid, idxk, w4, pre, pS2, pQ2, 4096, 512, 2048);
  gn_fused<128><<<dim3(8,2), 1024, 0, stream>>>(pre, g4, b4, F2a, 512);

  (void)in_sizes; (void)n_in; (void)out_size; (void)ws_size;
}

// Round 12
// 3289.522 us; speedup vs baseline: 1.0973x; 1.0788x over previous
//
#include <hip/hip_runtime.h>
#include <math.h>

typedef unsigned long long ull;

// ---------------------------------------------------------------------------
// FPS body (r7-proven scalar version): BLK threads, DPP wave-max + ballot +
// 1 barrier, double-buffered wave keys, pinned register coords.
// ---------------------------------------------------------------------------
template<int CTRL>
__device__ __forceinline__ float dpp_maxf(float x){
  int y = __builtin_amdgcn_update_dpp(0, __float_as_int(x), CTRL, 0xf, 0xf, true);
  return fmaxf(x, __int_as_float(y));
}

template<int PPT, int BLK, int M>
__device__ void fps_body(const float* __restrict__ P, int* __restrict__ idx_out,
                         int b, float* sm){
  constexpr int N  = PPT*BLK;
  constexpr int NW = BLK/64;
  float* lx = sm; float* ly = sm+N; float* lz = sm+2*N;
  ull* wk = (ull*)(sm + 3*N);
  int t = threadIdx.x;
  const float* Pb = P + (size_t)b*3*N;
  for (int i=t; i<N; i+=BLK){ lx[i]=Pb[i]; ly[i]=Pb[N+i]; lz[i]=Pb[2*N+i]; }
  __syncthreads();
  float px[PPT], py[PPT], pz[PPT], dist[PPT];
  #pragma unroll
  for (int j=0;j<PPT;j++){ int p=t*PPT+j; px[j]=lx[p]; py[j]=ly[p]; pz[j]=lz[p]; }
  #pragma unroll
  for (int j=0;j<PPT;j++){
    asm volatile("" : "+v"(px[j]), "+v"(py[j]), "+v"(pz[j]));
  }
  float sx = lx[0], sy = ly[0], sz = lz[0];
  float bd = -1.f; int bj = 0;
  #pragma unroll
  for (int j=0;j<PPT;j++){
    float dx=__fsub_rn(px[j],sx), dy=__fsub_rn(py[j],sy), dz=__fsub_rn(pz[j],sz);
    float dd=__fadd_rn(__fadd_rn(__fmul_rn(dx,dx),__fmul_rn(dy,dy)),__fmul_rn(dz,dz));
    dist[j]=dd;
    bool c = dd > bd; bd = c?dd:bd; bj = c?j:bj;
  }
  int pbest = t*PPT + bj;
  if (t==0) idx_out[(size_t)b*M] = 0;
  int wid = t>>6, lane = t&63, par = 0;
  for (int i=1;i<M;i++){
    float r = bd;
    r = dpp_maxf<0x111>(r); r = dpp_maxf<0x112>(r);
    r = dpp_maxf<0x114>(r); r = dpp_maxf<0x118>(r);
    r = dpp_maxf<0x142>(r); r = dpp_maxf<0x143>(r);
    float wmax = __int_as_float(__builtin_amdgcn_readlane(__float_as_int(r), 63));
    ull msk = __ballot(bd == wmax);
    int srcl = __ffsll(msk) - 1;            // lowest lane == lowest owned index
    int wp = __builtin_amdgcn_readlane(pbest, srcl);
    if (lane==0)
      wk[par*NW + wid] = ((ull)__float_as_uint(wmax)<<32)
                       | (unsigned)(~(unsigned)wp);
    __syncthreads();
    ull best = wk[par*NW];
    #pragma unroll
    for (int w=1;w<NW;w++){ ull o = wk[par*NW+w]; best = (o>best)?o:best; }
    unsigned widx = ~(unsigned)best;
    if (t==0) idx_out[(size_t)b*M + i] = (int)widx;
    float nsx = lx[widx], nsy = ly[widx], nsz = lz[widx];
    par ^= 1;
    float nbd = -1.f; int nbj = 0;
    #pragma unroll
    for (int j=0;j<PPT;j++){
      float dx=__fsub_rn(px[j],nsx), dy=__fsub_rn(py[j],nsy), dz=__fsub_rn(pz[j],nsz);
      float dd=__fadd_rn(__fadd_rn(__fmul_rn(dx,dx),__fmul_rn(dy,dy)),__fmul_rn(dz,dz));
      float nd = fminf(dist[j], dd);
      dist[j] = nd;
      bool c = nd > nbd; nbd = c?nd:nbd; nbj = c?j:nbj;
    }
    bd = nbd; pbest = t*PPT + nbj;
  }
}

// ---------------------------------------------------------------------------
// KNN body (scan + merge), dynamic-LDS version of the proven knn_fused.
// sm layout: tile 4096 f (16KB) | pd 4096 f | pi 4096 i  (48KB total)
// ---------------------------------------------------------------------------
__device__ void knn_body(const float* __restrict__ Pq, const float* __restrict__ Pp,
                         int* __restrict__ idxk, int Nq, int Np, int qb, int b,
                         float* smbase){
  float4* tile = (float4*)smbase;
  float*  pd   = smbase + 4096;
  int*    pi   = (int*)(smbase + 8192);
  int t = threadIdx.x, w = t>>6, l = t&63;
  int qn = qb*64 + l;
  const float* Pqb = Pq + (size_t)b*3*Nq;
  const float* Ppb = Pp + (size_t)b*3*Np;
  float qx = Pqb[qn], qy = Pqb[Nq+qn], qz = Pqb[2*Nq+qn];
  float qq = __fadd_rn(__fadd_rn(__fmul_rn(qx,qx),__fmul_rn(qy,qy)),__fmul_rn(qz,qz));

  float dl[16]; int il[16];
  #pragma unroll
  for (int u=0;u<16;u++){ dl[u]=INFINITY; il[u]=-1; }
  float maxd = INFINITY; int maxslot = 0;

  int CANDS = Np >> 2;
  int c0 = w*CANDS;
  for (int tb=0; tb<CANDS; tb+=256){
    __syncthreads();
    #pragma unroll
    for (int k=0;k<4;k++){
      int p = c0 + tb + k*64 + l;
      float px = Ppb[p], py = Ppb[Np+p], pz = Ppb[2*Np+p];
      float pp = __fadd_rn(__fadd_rn(__fmul_rn(px,px),__fmul_rn(py,py)),__fmul_rn(pz,pz));
      tile[w*256 + k*64 + l] = make_float4(px,py,pz,pp);
    }
    __syncthreads();
    for (int j=0;j<256;j++){
      float4 c = tile[w*256 + j];
      float dot = __fadd_rn(__fadd_rn(__fmul_rn(qx,c.x),__fmul_rn(qy,c.y)),__fmul_rn(qz,c.z));
      float dc  = __fsub_rn(__fadd_rn(qq,c.w), __fmul_rn(2.0f,dot));
      if (dc < maxd){
        int pidx = c0 + tb + j;
        #pragma unroll
        for (int u=0;u<16;u++){ bool sel=(maxslot==u); dl[u]=sel?dc:dl[u]; il[u]=sel?pidx:il[u]; }
        maxd = dl[0]; maxslot = 0;
        #pragma unroll
        for (int u=1;u<16;u++){ bool g=(dl[u]>maxd); maxd=g?dl[u]:maxd; maxslot=g?u:maxslot; }
      }
    }
  }
  #pragma unroll
  for (int u=0;u<16;u++){ pd[(u*4+w)*64 + l]=dl[u]; pi[(u*4+w)*64 + l]=il[u]; }
  __syncthreads();
  if (t < 64){
    int q = t;
    float mdl[16]; int mil[16];
    #pragma unroll
    for (int u=0;u<16;u++){ mdl[u]=INFINITY; mil[u]=0x7fffffff; }
    float mmaxd = INFINITY; int mmaxi = 0x7fffffff; int mslot = 0;
    for (int s=0;s<4;s++){
      #pragma unroll
      for (int u=0;u<16;u++){
        float d = pd[(u*4+s)*64 + q]; int ii = pi[(u*4+s)*64 + q];
        bool better = (d < mmaxd) || (d == mmaxd && ii < mmaxi);
        if (better){
          #pragma unroll
          for (int v=0;v<16;v++){ bool sel=(mslot==v); mdl[v]=sel?d:mdl[v]; mil[v]=sel?ii:mil[v]; }
          mmaxd = mdl[0]; mmaxi = mil[0]; mslot = 0;
          #pragma unroll
          for (int v=1;v<16;v++){
            bool g = (mdl[v]>mmaxd) || (mdl[v]==mmaxd && mil[v]>mmaxi);
            mmaxd=g?mdl[v]:mmaxd; mmaxi=g?mil[v]:mmaxi; mslot=g?v:mslot;
          }
        }
      }
    }
    #pragma unroll
    for (int u=0;u<16;u++)
      idxk[((size_t)b*Nq + qb*64 + q)*16 + u] = mil[u];
  }
}

// ---------------------------------------------------------------------------
// mega_a: fps1 (2 blocks) ∥ stem (64 blocks) ∥ knn1 (256 blocks)
// all roles read ONLY xyz; disjoint outputs -> no inter-block deps.
// ---------------------------------------------------------------------------
__global__ __launch_bounds__(256, 1) void mega_a(const float* __restrict__ xyz,
    const float* __restrict__ sw, const float* __restrict__ sb,
    float* __restrict__ F0, float* __restrict__ P0o,
    int* __restrict__ idxk, int* __restrict__ idx1){
  extern __shared__ __align__(16) float sm[];
  int bid = blockIdx.x;
  if (bid < 2){
    fps_body<32,256,2048>(xyz, idx1, bid, sm);
  } else if (bid < 66){
    int id = (bid-2)*256 + threadIdx.x;       // 0..16383
    int n = id & 8191, b = id >> 13;
    float x = xyz[((size_t)b*3+0)*8192+n];
    float y = xyz[((size_t)b*3+1)*8192+n];
    float z = xyz[((size_t)b*3+2)*8192+n];
    P0o[((size_t)b*3+0)*8192+n] = x;
    P0o[((size_t)b*3+1)*8192+n] = y;
    P0o[((size_t)b*3+2)*8192+n] = z;
    #pragma unroll
    for (int o=0;o<8;o++){
      float v = fmaf(sw[o*3+0],x, fmaf(sw[o*3+1],y, fmaf(sw[o*3+2],z, sb[o])));
      F0[((size_t)b*8+o)*8192+n] = v;
    }
  } else {
    int r = bid - 66;
    knn_body(xyz, xyz, idxk, 8192, 8192, r & 127, r >> 7, sm);
  }
}

// mega_b: fps2 (2 blocks) ∥ knn2 (64 blocks); both read P1o/xyz only.
__global__ __launch_bounds__(256, 1) void mega_b(const float* __restrict__ P1o,
    const float* __restrict__ xyz, int* __restrict__ idxk, int* __restrict__ idx2){
  extern __shared__ __align__(16) float sm[];
  int bid = blockIdx.x;
  if (bid < 2){
    fps_body<8,256,512>(P1o, idx2, bid, sm);
  } else {
    int r = bid - 2;
    knn_body(P1o, xyz, idxk, 2048, 8192, r & 31, r >> 5, sm);
  }
}

// stage-3 standalone knn (proven static-LDS kernel)
__global__ __launch_bounds__(256) void knn_fused(
    const float* __restrict__ Pq, const float* __restrict__ Pp,
    int* __restrict__ idxk, int Nq, int Np){
  __shared__ __align__(16) float smk[12288];
  knn_body(Pq, Pp, idxk, Nq, Np, blockIdx.x, blockIdx.y, smk);
}

// ---------------------------------------------------------------------------
// EdgeConv pre-activation + per-wave GN stats partials (proven)
// ---------------------------------------------------------------------------
template<int CIN, int COUT>
__global__ __launch_bounds__(1024) void edge_conv_pre(
    const float* __restrict__ Fk, const float* __restrict__ Fi,
    const int* __restrict__ idx, const float* __restrict__ W,
    float* __restrict__ pre, float* __restrict__ partS,
    float* __restrict__ partQ, int pstride, int Nq, int Np){
  constexpr int C2  = 2*CIN;
  constexpr int PAD = C2 + 4;
  constexpr int TO  = (COUT <= 64) ? COUT : 64;
  constexpr int OP  = COUT / TO;
  constexpr int CPG = COUT/8;
  constexpr int WPG = CPG/4;
  extern __shared__ float sm[];
  float* Wl = sm;
  float* Pl = sm + COUT*PAD;
  int t = threadIdx.x;
  int n = blockIdx.x, b = blockIdx.y;
  for (int e=t; e<COUT*C2; e += blockDim.x){
    int o=e/C2, c=e%C2; Wl[o*PAD+c] = W[e];
  }
  const int* idxn = idx + ((size_t)b*Nq + n)*16;
  for (int e=t; e<16*C2; e += blockDim.x){
    int k = e/C2, c = e%C2;
    int cc = (c < CIN) ? c : (c-CIN);
    float fi = Fi[((size_t)b*CIN + cc)*Nq + n];
    float v;
    if (c < CIN){ int nb = idxn[k]; v = Fk[((size_t)b*CIN + c)*Np + nb] - fi; }
    else v = fi;
    Pl[k*PAD+c] = v;
  }
  __syncthreads();
  int k = t & 15, o0 = t >> 4;
  float accv[OP];
  #pragma unroll
  for (int op=0; op<OP; op++){
    int o = o0 + op*TO;
    float acc = 0.f;
    #pragma unroll
    for (int c=0;c<C2;c+=4){
      float4 wv = *(const float4*)&Wl[o*PAD+c];
      float4 pv = *(const float4*)&Pl[k*PAD+c];
      acc = fmaf(wv.x,pv.x,acc); acc = fmaf(wv.y,pv.y,acc);
      acc = fmaf(wv.z,pv.z,acc); acc = fmaf(wv.w,pv.w,acc);
    }
    accv[op] = acc;
    pre[(((size_t)b*COUT + o)*Nq + n)*16 + k] = acc;
  }
  int w = t>>6;
  #pragma unroll
  for (int op=0; op<OP; op++){
    float s1 = accv[op], s2 = accv[op]*accv[op];
    #pragma unroll
    for (int off=32; off>=1; off>>=1){ s1 += __shfl_down(s1,off); s2 += __shfl_down(s2,off); }
    if ((t&63)==0){
      int o = o0 + op*TO;
      int g = o / CPG;
      int slot = n*WPG + (w % WPG);
      partS[((size_t)(b*8+g))*pstride + slot] = s1;
      partQ[((size_t)(b*8+g))*pstride + slot] = s2;
    }
  }
}

// combine partials -> per-(b,g) mu, rstd
__global__ __launch_bounds__(256) void gn_combine(const float* __restrict__ partS,
    const float* __restrict__ partQ, float2* __restrict__ stats,
    int nslot, int pstride, double cnt){
  int bg = blockIdx.x, t = threadIdx.x;
  const float* ps = partS + (size_t)bg*pstride;
  const float* pq = partQ + (size_t)bg*pstride;
  double s=0.0, q=0.0;
  for (int i=t; i<nslot; i+=256){ s += (double)ps[i]; q += (double)pq[i]; }
  #pragma unroll
  for (int off=32; off>=1; off>>=1){ s += __shfl_down(s,off); q += __shfl_down(q,off); }
  __shared__ double ls[4], lq[4];
  int wid = t>>6;
  if ((t&63)==0){ ls[wid]=s; lq[wid]=q; }
  __syncthreads();
  if (t==0){
    double S=ls[0]+ls[1]+ls[2]+ls[3], Q=lq[0]+lq[1]+lq[2]+lq[3];
    double mu = S/cnt;
    double var = Q/cnt - mu*mu;
    stats[bg] = make_float2((float)mu, (float)(1.0/sqrt(var+1e-5)));
  }
}

// normalize + affine + relu + max over K
template<int COUT>
__global__ __launch_bounds__(256) void gn_apply(const float* __restrict__ pre,
    const float2* __restrict__ stats, const float* __restrict__ gamma,
    const float* __restrict__ beta, float* __restrict__ outF, int Nq){
  int id = blockIdx.x*256 + threadIdx.x;
  int o = (id/Nq)%COUT; int b = id/(Nq*COUT);
  int g = o/(COUT/8);
  float2 st = stats[b*8+g];
  float muf = st.x, rstd = st.y;
  float ga=gamma[o], be=beta[o];
  const float4* p = (const float4*)(pre + (size_t)id*16);
  float m = 0.f;
  #pragma unroll
  for (int q=0;q<4;q++){
    float4 v = p[q];
    m = fmaxf(m, fmaf((v.x-muf)*rstd, ga, be));
    m = fmaxf(m, fmaf((v.y-muf)*rstd, ga, be));
    m = fmaxf(m, fmaf((v.z-muf)*rstd, ga, be));
    m = fmaxf(m, fmaf((v.w-muf)*rstd, ga, be));
  }
  outF[id] = m;
}

// single-kernel GN for small stages (pre is L2-resident)
template<int COUT>
__global__ __launch_bounds__(1024) void gn_fused(const float* __restrict__ pre,
    const float* __restrict__ gamma, const float* __restrict__ beta,
    float* __restrict__ outF, int Nq){
  constexpr int CPG = COUT/8;
  int g = blockIdx.x, b = blockIdx.y, t = threadIdx.x;
  size_t base = (((size_t)b*COUT + g*CPG)*(size_t)Nq)*16;
  const float* p = pre + base;
  int len = CPG*Nq*16;
  double s=0.0, sq=0.0;
  for (int i = t*4; i < len; i += 4096){
    float4 v = *(const float4*)(p+i);
    s += (double)v.x; sq = fma((double)v.x,(double)v.x,sq);
    s += (double)v.y; sq = fma((double)v.y,(double)v.y,sq);
    s += (double)v.z; sq = fma((double)v.z,(double)v.z,sq);
    s += (double)v.w; sq = fma((double)v.w,(double)v.w,sq);
  }
  #pragma unroll
  for (int off=32; off>=1; off>>=1){ s += __shfl_down(s, off); sq += __shfl_down(sq, off); }
  __shared__ double ls[16], lq[16];
  __shared__ float stats[2];
  int wid = t>>6;
  if ((t&63)==0){ ls[wid]=s; lq[wid]=sq; }
  __syncthreads();
  if (t==0){
    double S=0.0, Q=0.0;
    #pragma unroll
    for (int w=0;w<16;w++){ S+=ls[w]; Q+=lq[w]; }
    double cnt = (double)CPG*(double)Nq*16.0;
    double mu  = S/cnt;
    double var = Q/cnt - mu*mu;
    stats[0] = (float)mu;
    stats[1] = (float)(1.0/sqrt(var+1e-5));
  }
  __syncthreads();
  float muf = stats[0], rstd = stats[1];
  int outs = CPG*Nq;
  for (int e=t; e<outs; e+=1024){
    int ol = e/Nq, n = e - ol*Nq;
    int o = g*CPG + ol;
    float ga = gamma[o], be = beta[o];
    const float4* pp = (const float4*)(p + (size_t)e*16);
    float m = 0.f;
    #pragma unroll
    for (int q=0;q<4;q++){
      float4 v = pp[q];
      m = fmaxf(m, fmaf((v.x-muf)*rstd, ga, be));
      m = fmaxf(m, fmaf((v.y-muf)*rstd, ga, be));
      m = fmaxf(m, fmaf((v.z-muf)*rstd, ga, be));
      m = fmaxf(m, fmaf((v.w-muf)*rstd, ga, be));
    }
    outF[((size_t)b*COUT + o)*Nq + n] = m;
  }
}

// fused gather: P (C=3) and F (C=CF) in one dispatch
__global__ __launch_bounds__(256) void gather_fused(float* __restrict__ Pdst,
    const float* __restrict__ Psrc, float* __restrict__ Fdst,
    const float* __restrict__ Fsrc, const int* __restrict__ idxv,
    int CF, int Nsrc, int M){
  int per = (3+CF)*M;
  int total = 2*per;
  for (int id = blockIdx.x*256 + threadIdx.x; id < total; id += gridDim.x*256){
    int b = id/per, r = id%per, c = r/M, m = r%M;
    int sn = idxv[(size_t)b*M + m];
    if (c < 3)
      Pdst[((size_t)b*3+c)*M+m] = Psrc[((size_t)b*3+c)*Nsrc+sn];
    else {
      int cf = c-3;
      Fdst[((size_t)b*CF+cf)*M+m] = Fsrc[((size_t)b*CF+cf)*Nsrc+sn];
    }
  }
}

// ---------------------------------------------------------------------------
extern "C" void kernel_launch(void* const* d_in, const int* in_sizes, int n_in,
                              void* d_out, int out_size, void* d_ws, size_t ws_size,
                              hipStream_t stream) {
  const float* xyz    = (const float*)d_in[0];
  const float* stem_w = (const float*)d_in[1];
  const float* stem_b = (const float*)d_in[2];
  const float* w1 = (const float*)d_in[3];
  const float* g1 = (const float*)d_in[4];
  const float* b1 = (const float*)d_in[5];
  const float* w2 = (const float*)d_in[6];
  const float* g2 = (const float*)d_in[7];
  const float* b2 = (const float*)d_in[8];
  const float* w3 = (const float*)d_in[9];
  const float* g3 = (const float*)d_in[10];
  const float* b3 = (const float*)d_in[11];
  const float* w4 = (const float*)d_in[12];
  const float* g4 = (const float*)d_in[13];
  const float* b4 = (const float*)d_in[14];

  float* out = (float*)d_out;
  float* P0o  = out + 0;
  float* F0a  = out + 49152;
  float* P1o  = out + 573440;
  float* F1a  = out + 585728;
  float* P2o  = out + 847872;
  float* F2a  = out + 850944;

  char* ws = (char*)d_ws;
  float* F0     = (float*)(ws + 0);            // 512 KB
  float* pre    = (float*)(ws + 524288);       // up to 33.5 MB
  int*   idxk   = (int*)  (ws + 34078720);     // 1 MB
  float2* stats = (float2*)(ws + 35127296);    // 128 B
  int*   idx1   = (int*)  (ws + 35127424);     // 16 KB
  int*   idx2   = (int*)  (ws + 35143808);     // 4 KB
  float* F1sk   = (float*)(ws + 35147904);     // 512 KB
  float* F2sk   = (float*)(ws + 35672192);     // 256 KB
  float* F2mid  = (float*)(ws + 35934336);     // 256 KB
  float* pS1 = (float*)(ws + 35147904);        // stage-1 partials (overlap F1sk/F2sk — dead then)
  float* pQ1 = (float*)(ws + 35672192);
  float* pS2 = (float*)(ws + 17825792);        // stage-2..4 partials (pre tail)
  float* pQ2 = (float*)(ws + 18087936);

  size_t smem_c1 = (size_t)(32*20  + 16*20 )*4;
  size_t smem_c2 = (size_t)(64*68  + 16*68 )*4;
  size_t smem_c3 = (size_t)(64*132 + 16*132)*4;
  size_t smem_c4 = (size_t)(128*132+ 16*132)*4;
  size_t smem_ma = (size_t)3*8192*4 + 256;     // fps1 needs most; knn uses 48KB
  size_t smem_mb = (size_t)49152 + 256;        // max(knn 48KB, fps2 ~24KB)

  // ---- launch 1: fps1 ∥ stem ∥ knn1 (all xyz-only)
  mega_a<<<322, 256, smem_ma, stream>>>(xyz, stem_w, stem_b, F0, P0o, idxk, idx1);

  // ---- stage 1 tail
  edge_conv_pre<8,32><<<dim3(8192,2), 512, smem_c1, stream>>>(F0, F0, idxk, w1, pre, pS1, pQ1, 8192, 8192, 8192);
  gn_combine<<<16, 256, 0, stream>>>(pS1, pQ1, stats, 8192, 8192, 524288.0);
  gn_apply<32><<<2048, 256, 0, stream>>>(pre, stats, g1, b1, F0a, 8192);
  gather_fused<<<560, 256, 0, stream>>>(P1o, xyz, F1sk, F0a, idx1, 32, 8192, 2048);

  // ---- launch 2: fps2 ∥ knn2
  mega_b<<<66, 256, smem_mb, stream>>>(P1o, xyz, idxk, idx2);

  // ---- stage 2 tail
  edge_conv_pre<32,64><<<dim3(2048,2), 1024, smem_c2, stream>>>(F0a, F1sk, idxk, w2, pre, pS2, pQ2, 4096, 2048, 8192);
  gn_combine<<<16, 256, 0, stream>>>(pS2, pQ2, stats, 4096, 4096, 262144.0);
  gn_apply<64><<<1024, 256, 0, stream>>>(pre, stats, g2, b2, F1a, 2048);
  gather_fused<<<268, 256, 0, stream>>>(P2o, P1o, F2sk, F1a, idx2, 64, 2048, 512);

  // ---- stage 3
  knn_fused<<<dim3(8,2), 256, 0, stream>>>(P2o, P1o, idxk, 512, 2048);
  edge_conv_pre<64,64><<<dim3(512,2), 1024, smem_c3, stream>>>(F1a, F2sk, idxk, w3, pre, pS2, pQ2, 4096, 512, 2048);
  gn_fused<64><<<dim3(8,2), 1024, 0, stream>>>(pre, g3, b3, F2mid, 512);

  // ---- stage 4 (same knn idx)
  edge_conv_pre<64,128><<<dim3(512,2), 1024, smem_c4, stream>>>(F1a, F2mid, idxk, w4, pre, pS2, pQ2, 4096, 512, 2048);
  gn_fused<128><<<dim3(8,2), 1024, 0, stream>>>(pre, g4, b4, F2a, 512);

  (void)in_sizes; (void)n_in; (void)out_size; (void)ws_size;
}